// Round 10
// baseline (189.766 us; speedup 1.0000x reference)
//
#include <hip/hip_runtime.h>
#include <math.h>

// LayerSumSimple: K-level chained cummax-of-sums == max-plus affine scan with
// 8-element state s:  s[k] <- max(s[k], s[k-1] + g_k(t)),  g_k = x*w[k]+b[k].
// 3 launches (no cooperative launch — round 9's coop capacity check failed
// silently; kernel boundaries give the needed producer->consumer visibility):
//   pass1 : per-chunk max-plus affine summary (C=128, L=64), f4-plane stores
//   pass2a: compose G=8 chunk maps -> NG=16 group maps per batch
//   pass3 : self-computed inflow (<=15 group + <=7 chunk applies, ring-2
//           prefetch), then scan own chunk, write output.
// Map storage = float4-PLANE layout: region r, plane i (i=0..8) holds entries
// [4i..4i+3] for channel d at float4 index r*9*DD + i*DD + d.  Lane-adjacent
// float4s -> fully coalesced 1KB lines (NOT round-5's per-thread transpose).
namespace {
constexpr int BB   = 8;
constexpr int TT   = 8192;
constexpr int DD   = 256;
constexpr int KK   = 8;
constexpr int TOUT = TT - KK + 1;       // 8185
constexpr int NSUM = 36;                // 8 c-vec + 28 strict-lower A = 9 float4
constexpr int C    = 128;               // chunks per sequence
constexpr int L    = TT / C;            // 64
constexpr int G    = 8;                 // chunks per group
constexpr int NG   = C / G;             // 16
constexpr int U    = 8;                 // pipeline batch (steps)
constexpr int NB   = L / U;             // 8 batches per chunk

__host__ __device__ __forceinline__ constexpr int tri(int k, int j) {
    return 8 + k * (k - 1) / 2 + j;     // k in [1,8), j < k  (max 35)
}

// one time-step of the summary recurrence (descending k uses OLD row k-1)
__device__ __forceinline__ void step_sum(float x, const float (&wk)[KK],
                                         const float (&bk)[KK],
                                         float (&A)[KK][KK], float (&cv)[KK])
{
    float g[KK];
    #pragma unroll
    for (int k = 0; k < KK; ++k) g[k] = fmaf(x, wk[k], bk[k]);
    #pragma unroll
    for (int k = KK - 1; k >= 1; --k) {
        #pragma unroll
        for (int j = 0; j < k - 1; ++j)
            A[k][j] = fmaxf(A[k][j], g[k] + A[k - 1][j]);
        A[k][k - 1] = fmaxf(A[k][k - 1], g[k]);  // A[k-1][k-1] == 0 (diag)
        cv[k] = fmaxf(cv[k], g[k] + cv[k - 1]);
    }
    cv[0] = fmaxf(cv[0], g[0]);
}

// f4-plane map load/store: 9 coalesced dwordx4 per map
__device__ __forceinline__ void ld_map4(const float4* __restrict__ base4,
                                        int r, int d, float (&m)[NSUM])
{
    const float4* p = base4 + r * (9 * DD) + d;
    float4* m4 = (float4*)m;
    #pragma unroll
    for (int i = 0; i < 9; ++i) m4[i] = p[i * DD];
}

__device__ __forceinline__ void st_map4(float4* __restrict__ base4,
                                        int r, int d, const float (&m)[NSUM])
{
    float4* p = base4 + r * (9 * DD) + d;
    const float4* m4 = (const float4*)m;
    #pragma unroll
    for (int i = 0; i < 9; ++i) p[i * DD] = m4[i];
}

// s <- apply(map m, s)
__device__ __forceinline__ void apply_map(const float (&m)[NSUM], float (&s)[KK])
{
    float ns[KK];
    #pragma unroll
    for (int k = 0; k < KK; ++k) ns[k] = fmaxf(m[k], s[k]);   // c[k], diag
    #pragma unroll
    for (int k = 1; k < KK; ++k) {
        #pragma unroll
        for (int j = 0; j < k; ++j) ns[k] = fmaxf(ns[k], m[tri(k, j)] + s[j]);
    }
    #pragma unroll
    for (int k = 0; k < KK; ++k) s[k] = ns[k];
}

// (R,cv) <- compose(map m, (R,cv))   [m applied AFTER accumulated (R,cv)]
__device__ __forceinline__ void compose_map(const float (&m)[NSUM],
                                            float (&R)[KK][KK], float (&cv)[KK])
{
    float nc[KK];
    #pragma unroll
    for (int i = 0; i < KK; ++i) {
        float v = fmaxf(m[i], cv[i]);
        #pragma unroll
        for (int j = 0; j < i; ++j) v = fmaxf(v, m[tri(i, j)] + cv[j]);
        nc[i] = v;
    }
    float nR[KK][KK];
    #pragma unroll
    for (int i = 1; i < KK; ++i) {
        #pragma unroll
        for (int j = 0; j < i; ++j) {
            float v = fmaxf(R[i][j], m[tri(i, j)]);
            #pragma unroll
            for (int mm = j + 1; mm < i; ++mm)
                v = fmaxf(v, m[tri(i, mm)] + R[mm][j]);
            nR[i][j] = v;
        }
    }
    #pragma unroll
    for (int i = 0; i < KK; ++i) {
        cv[i] = nc[i];
        #pragma unroll
        for (int j = 0; j < i; ++j) R[i][j] = nR[i][j];
    }
}

// ring-2 serial apply of n consecutive map regions r0..r0+n-1 (chronological)
__device__ __forceinline__ void apply_chain(const float4* __restrict__ base4,
                                            int r0, int n, int d, float (&s)[KK])
{
    if (n <= 0) return;
    float m0[NSUM], m1[NSUM];
    ld_map4(base4, r0, d, m0);
    int i = 0;
    #pragma unroll 1
    for (;;) {
        if (i + 1 < n) ld_map4(base4, r0 + i + 1, d, m1);
        apply_map(m0, s);
        if (++i >= n) break;
        if (i + 1 < n) ld_map4(base4, r0 + i + 1, d, m0);
        apply_map(m1, s);
        if (++i >= n) break;
    }
}

// one time-step of the plain scan
__device__ __forceinline__ void step_scan(float x, const float (&wk)[KK],
                                          const float (&bk)[KK], float (&s)[KK])
{
    float g[KK];
    #pragma unroll
    for (int k = 0; k < KK; ++k) g[k] = fmaf(x, wk[k], bk[k]);
    #pragma unroll
    for (int k = KK - 1; k >= 1; --k) s[k] = fmaxf(s[k], s[k - 1] + g[k]);
    s[0] = fmaxf(s[0], g[0]);
}

// ---- pass 1: one block per (b, chunk); thread d = channel ----
__global__ __launch_bounds__(256) void pass1_summaries(
    const float* __restrict__ X, const float* __restrict__ W,
    const float* __restrict__ Bv, float* __restrict__ sum)
{
    const int bid = blockIdx.x;             // b*C + c
    const int b = bid / C;
    const int c = bid % C;
    const int d = threadIdx.x;

    float wk[KK], bk[KK];
    #pragma unroll
    for (int k = 0; k < KK; ++k) { wk[k] = W[k * DD + d]; bk[k] = Bv[k * DD + d]; }

    float cv[KK];
    float A[KK][KK];
    #pragma unroll
    for (int k = 0; k < KK; ++k) {
        cv[k] = -INFINITY;
        #pragma unroll
        for (int j = 0; j < KK; ++j) A[k][j] = -INFINITY;
    }

    const float* xp = X + (b * TT + c * L) * DD + d;
    float x0[U], x1[U];
    #pragma unroll
    for (int u = 0; u < U; ++u) x0[u] = xp[u * DD];

    #pragma unroll 1
    for (int ib = 0; ib + 2 < NB; ib += 2) {
        #pragma unroll
        for (int u = 0; u < U; ++u) x1[u] = xp[(U + u) * DD];
        #pragma unroll
        for (int u = 0; u < U; ++u) step_sum(x0[u], wk, bk, A, cv);
        #pragma unroll
        for (int u = 0; u < U; ++u) x0[u] = xp[(2 * U + u) * DD];
        #pragma unroll
        for (int u = 0; u < U; ++u) step_sum(x1[u], wk, bk, A, cv);
        xp += 2 * U * DD;
    }
    #pragma unroll
    for (int u = 0; u < U; ++u) x1[u] = xp[(U + u) * DD];
    #pragma unroll
    for (int u = 0; u < U; ++u) step_sum(x0[u], wk, bk, A, cv);
    #pragma unroll
    for (int u = 0; u < U; ++u) step_sum(x1[u], wk, bk, A, cv);

    alignas(16) float o[NSUM];
    #pragma unroll
    for (int k = 0; k < KK; ++k) o[k] = cv[k];
    #pragma unroll
    for (int k = 1; k < KK; ++k) {
        #pragma unroll
        for (int j = 0; j < k; ++j) o[tri(k, j)] = A[k][j];
    }
    st_map4((float4*)sum, bid, d, o);
}

// ---- pass 2a: one block per (b, group); compose G chunk maps ----
__global__ __launch_bounds__(256) void pass2a_groups(
    const float* __restrict__ sum, float* __restrict__ gsum)
{
    const int bid = blockIdx.x;             // b*NG + g
    const int b = bid / NG;
    const int g = bid % NG;
    const int d = threadIdx.x;
    const float4* sum4 = (const float4*)sum;

    float R[KK][KK], cv[KK];
    #pragma unroll
    for (int i = 0; i < KK; ++i) {
        cv[i] = -INFINITY;
        #pragma unroll
        for (int j = 0; j < KK; ++j) R[i][j] = -INFINITY;
    }

    const int r0 = b * C + g * G;
    float m0[NSUM], m1[NSUM];
    ld_map4(sum4, r0, d, m0);
    #pragma unroll 1
    for (int ci = 0; ci + 2 < G; ci += 2) {
        ld_map4(sum4, r0 + ci + 1, d, m1);
        compose_map(m0, R, cv);
        ld_map4(sum4, r0 + ci + 2, d, m0);
        compose_map(m1, R, cv);
    }
    ld_map4(sum4, r0 + G - 1, d, m1);
    compose_map(m0, R, cv);
    compose_map(m1, R, cv);

    alignas(16) float o[NSUM];
    #pragma unroll
    for (int i = 0; i < KK; ++i) o[i] = cv[i];
    #pragma unroll
    for (int i = 1; i < KK; ++i) {
        #pragma unroll
        for (int j = 0; j < i; ++j) o[tri(i, j)] = R[i][j];
    }
    st_map4((float4*)gsum, bid, d, o);
}

// ---- pass 3: one block per (b, chunk); self-inflow + scan + output ----
__global__ __launch_bounds__(256, 4) void pass3_scan(
    const float* __restrict__ X, const float* __restrict__ W,
    const float* __restrict__ Bv, const float* __restrict__ sum,
    const float* __restrict__ gsum, float* __restrict__ out)
{
    const int bid = blockIdx.x;             // b*C + c
    const int b = bid / C;
    const int c = bid % C;
    const int d = threadIdx.x;

    float wk[KK], bk[KK];
    #pragma unroll
    for (int k = 0; k < KK; ++k) { wk[k] = W[k * DD + d]; bk[k] = Bv[k * DD + d]; }

    // self-computed inflow: groups 0..g-1, then chunks g*G..c-1
    float s[KK];
    #pragma unroll
    for (int k = 0; k < KK; ++k) s[k] = -INFINITY;
    const int g = c / G;
    apply_chain((const float4*)gsum, b * NG, g, d, s);
    apply_chain((const float4*)sum, b * C + g * G, c - g * G, d, s);

    const int t0 = c * L;
    const float* xp = X + (b * TT + t0) * DD + d;
    // fixed base: indexed by cumulative in-chunk step t only (never advances)
    float* op = out + b * TOUT * DD + (t0 - (KK - 1)) * DD + d;

    float x0[U], x1[U];
    #pragma unroll
    for (int u = 0; u < U; ++u) x0[u] = xp[u * DD];

    int t = 0;
    #pragma unroll 1
    for (int ib = 0; ib + 2 < NB; ib += 2) {
        #pragma unroll
        for (int u = 0; u < U; ++u) x1[u] = xp[(U + u) * DD];
        #pragma unroll
        for (int u = 0; u < U; ++u) {
            step_scan(x0[u], wk, bk, s);
            if (t0 + t >= KK - 1) op[t * DD] = s[KK - 1];
            ++t;
        }
        #pragma unroll
        for (int u = 0; u < U; ++u) x0[u] = xp[(2 * U + u) * DD];
        #pragma unroll
        for (int u = 0; u < U; ++u) {
            step_scan(x1[u], wk, bk, s);
            if (t0 + t >= KK - 1) op[t * DD] = s[KK - 1];
            ++t;
        }
        xp += 2 * U * DD;
    }
    #pragma unroll
    for (int u = 0; u < U; ++u) x1[u] = xp[(U + u) * DD];
    #pragma unroll
    for (int u = 0; u < U; ++u) {
        step_scan(x0[u], wk, bk, s);
        if (t0 + t >= KK - 1) op[t * DD] = s[KK - 1];
        ++t;
    }
    #pragma unroll
    for (int u = 0; u < U; ++u) {
        step_scan(x1[u], wk, bk, s);
        if (t0 + t >= KK - 1) op[t * DD] = s[KK - 1];
        ++t;
    }
}
} // namespace

extern "C" void kernel_launch(void* const* d_in, const int* in_sizes, int n_in,
                              void* d_out, int out_size, void* d_ws, size_t ws_size,
                              hipStream_t stream)
{
    const float* X  = (const float*)d_in[0];
    const float* W  = (const float*)d_in[1];
    const float* Bv = (const float*)d_in[2];
    float* out = (float*)d_out;

    // ws: sum 37.7 MB + gsum 4.7 MB
    float* sum  = (float*)d_ws;
    float* gsum = sum + (size_t)BB * C * NSUM * DD;

    pass1_summaries<<<BB * C, 256, 0, stream>>>(X, W, Bv, sum);
    pass2a_groups<<<BB * NG, 256, 0, stream>>>(sum, gsum);
    pass3_scan<<<BB * C, 256, 0, stream>>>(X, W, Bv, sum, gsum, out);
}